// Round 2
// baseline (7717.916 us; speedup 1.0000x reference)
//
#include <hip/hip_runtime.h>

typedef unsigned long long u64;
typedef unsigned int u32;

#define NB 8
#define NPIX 65536   // 256*256

// monotone float->uint encoding (order-preserving for all reals)
__device__ __forceinline__ u32 fsort(float f){
  u32 u = __float_as_uint(f);
  return (u & 0x80000000u) ? ~u : (u | 0x80000000u);
}
__device__ __forceinline__ float funsort(u32 s){
  u32 u = (s & 0x80000000u) ? (s ^ 0x80000000u) : ~s;
  return __uint_as_float(u);
}

// ---------------- init: zero packed best-map, init use map + pos sentinels ----
__global__ void init_kernel(u64* __restrict__ packed, float* __restrict__ u,
                            int* __restrict__ pxy){
  int idx = blockIdx.x * 256 + threadIdx.x;
  if (idx < NB * NPIX){
    packed[idx] = 0ull;
    int p = idx & (NPIX - 1);
    int x = p >> 8, y = p & 255;
    u[idx] = (x >= 16 && x < 240 && y >= 16 && y < 240) ? 1.0f : 0.0f;
  }
  if (idx < 2 * NB) pxy[idx] = -100000;  // sentinel: first iter tmap==1 everywhere
}

// ---------------- conv + per-pixel max over d (fused) -----------------------
// conv[b,d,x,y] = sum_{fy,fx} input[b,(x+fy-16)%256,(y+fx-16)%256] * filt[d,fy,fx]
// 64x64 output tile per block, 16 d's; rolling 4-row register window over fy;
// filter rows via wave-uniform (scalar) global loads -> SGPR operand of v_fma.
__global__ __launch_bounds__(256, 2) void conv_best_kernel(
    const float* __restrict__ input, const float* __restrict__ filt,
    const float* __restrict__ prior, u64* __restrict__ packed)
{
  __shared__ float sin_[96 * 96];
  const int tile = blockIdx.x;        // 0..15
  const int b    = blockIdx.y;        // 0..7
  const int g    = blockIdx.z;        // 0..3 (16 d's each)
  const int tX = (tile >> 2) << 6;
  const int tY = (tile & 3) << 6;
  const int tid = threadIdx.x;

  const float* inb = input + b * NPIX;
  for (int k = tid; k < 96 * 96; k += 256){
    int iy = k / 96, ix = k - iy * 96;
    int gx = (tX + iy - 16) & 255;
    int gy = (tY + ix - 16) & 255;
    sin_[k] = inb[(gx << 8) + gy];
  }
  __syncthreads();

  const int ty = tid >> 4, tx = tid & 15;
  const int oy = ty << 2, ox = tx << 2;

  float bv[16];
  int   bd[16];
  #pragma unroll
  for (int i = 0; i < 16; ++i){ bv[i] = -3e38f; bd[i] = 0; }

  float w[4][36];   // rolling input rows; ALL indices compile-time constants

  for (int dl = 0; dl < 16; ++dl){
    const int d = (g << 4) + dl;
    const float* __restrict__ frow = filt + d * 1089;

    // prologue: rows oy..oy+3 -> slots 0..3
    #pragma unroll
    for (int j = 0; j < 4; ++j){
      const float4* src = (const float4*)(sin_ + (oy + j) * 96 + ox);
      #pragma unroll
      for (int q = 0; q < 9; ++q){
        float4 t = src[q];
        w[j][4*q+0] = t.x; w[j][4*q+1] = t.y; w[j][4*q+2] = t.z; w[j][4*q+3] = t.w;
      }
    }

    float acc[4][4] = {};

    // phase: window rows are slots ((P)+r)&3; after use, slot (P)&3 gets row oy+fy+4
#define CPHASE(P, DOLOAD)                                                    \
    {                                                                        \
      const int fy = fy4 + (P);                                              \
      const float* fr = frow + fy * 33;   /* wave-uniform -> s_load */       \
      _Pragma("unroll")                                                      \
      for (int fx = 0; fx < 33; ++fx){                                       \
        const float fv = fr[fx];                                             \
        _Pragma("unroll")                                                    \
        for (int r = 0; r < 4; ++r){                                         \
          _Pragma("unroll")                                                  \
          for (int c = 0; c < 4; ++c)                                        \
            acc[r][c] = fmaf(fv, w[((P) + r) & 3][fx + c], acc[r][c]);       \
        }                                                                    \
      }                                                                      \
      if (DOLOAD){                                                           \
        const float4* src = (const float4*)(sin_ + (oy + fy + 4) * 96 + ox); \
        _Pragma("unroll")                                                    \
        for (int q = 0; q < 9; ++q){                                         \
          float4 t = src[q];                                                 \
          w[(P)&3][4*q+0] = t.x; w[(P)&3][4*q+1] = t.y;                      \
          w[(P)&3][4*q+2] = t.z; w[(P)&3][4*q+3] = t.w;                      \
        }                                                                    \
      }                                                                      \
    }

    #pragma unroll 1
    for (int fy4 = 0; fy4 < 32; fy4 += 4){
      CPHASE(0, true)
      CPHASE(1, true)
      CPHASE(2, true)
      CPHASE(3, true)
    }
    { const int fy4 = 32; CPHASE(0, false) }
#undef CPHASE

    const float pr = prior[d];
    #pragma unroll
    for (int r = 0; r < 4; ++r)
      #pragma unroll
      for (int c = 0; c < 4; ++c){
        float v = acc[r][c] * pr;
        int i = (r << 2) + c;
        if (v > bv[i]){ bv[i] = v; bd[i] = d; }   // ascending d: strict > keeps smallest d
      }
  }

  u64* pb = packed + b * NPIX;
  #pragma unroll
  for (int r = 0; r < 4; ++r)
    #pragma unroll
    for (int c = 0; c < 4; ++c){
      int x = tX + oy + r, y = tY + ox + c;
      int i = (r << 2) + c;
      u64 key = ((u64)fsort(bv[i]) << 32) | (u64)(63 - bd[i]); // tie -> smaller d
      atomicMax(&pb[(x << 8) + y], key);
    }
}

// ---------------- per-iteration: apply deadzone, scan for argmax + umax -----
__global__ __launch_bounds__(256) void scan_kernel(
    const u64* __restrict__ packed, float* __restrict__ u, const int* __restrict__ pxy,
    float* __restrict__ smax, int* __restrict__ sidx, float* __restrict__ umax)
{
  const int b   = blockIdx.y;
  const int blk = blockIdx.x;          // 0..31
  const int tid = threadIdx.x;
  const int px = pxy[2 * b], py = pxy[2 * b + 1];
  const int base = blk * 2048;

  float lmax = -3e38f; int lidx = 0; float lu = 0.f;
  for (int k = tid; k < 2048; k += 256){
    const int p = base + k;
    const int idx = b * NPIX + p;
    float uu = u[idx];
    int x = p >> 8, y = p & 255;
    float dx = (float)(x - px), dy = (float)(y - py);
    float d2 = dx * dx + dy * dy;
    float t = 1.f - __expf(d2 * -0.03125f);     // 1/(2*sigma^2), sigma=4
    if (d2 <= 16.f) t = 0.f;                    // hard cutout r=4
    uu *= t;
    u[idx] = uu;
    float bvv = funsort((u32)(packed[idx] >> 32));
    float s = bvv * uu;
    if (s > lmax || (s == lmax && p < lidx)){ lmax = s; lidx = p; }
    if (uu > lu) lu = uu;
  }
  __shared__ float rmax[256]; __shared__ int rid[256]; __shared__ float rum[256];
  rmax[tid] = lmax; rid[tid] = lidx; rum[tid] = lu;
  __syncthreads();
  for (int s = 128; s > 0; s >>= 1){
    if (tid < s){
      float v2 = rmax[tid + s]; int i2 = rid[tid + s];
      if (v2 > rmax[tid] || (v2 == rmax[tid] && i2 < rid[tid])){ rmax[tid] = v2; rid[tid] = i2; }
      if (rum[tid + s] > rum[tid]) rum[tid] = rum[tid + s];
    }
    __syncthreads();
  }
  if (tid == 0){
    smax[b * 32 + blk] = rmax[0];
    sidx[b * 32 + blk] = rid[0];
    umax[b * 32 + blk] = rum[0];
  }
}

// ---------------- finalize iteration: reduce 32 partials, emit outputs ------
__global__ void final_kernel(const u64* __restrict__ packed, const float* __restrict__ prior,
    const float* __restrict__ smax, const int* __restrict__ sidx, const float* __restrict__ umax,
    int* __restrict__ pxy, float* __restrict__ out, int t)
{
  const int b = blockIdx.x;
  const int lane = threadIdx.x;   // 64 threads, entries in lanes 0..31
  float v = -3e38f; int id = 0x7fffffff; float um = 0.f;
  if (lane < 32){ v = smax[b * 32 + lane]; id = sidx[b * 32 + lane]; um = umax[b * 32 + lane]; }
  #pragma unroll
  for (int off = 32; off > 0; off >>= 1){
    float v2 = __shfl_down(v, off);
    int   i2 = __shfl_down(id, off);
    float u2 = __shfl_down(um, off);
    if (v2 > v || (v2 == v && i2 < id)){ v = v2; id = i2; }
    if (u2 > um) um = u2;
  }
  if (lane == 0){
    int x = id >> 8, y = id & 255;
    u64 key = packed[b * NPIX + id];
    int d = 63 - (int)(key & 63ull);
    float bvv = funsort((u32)(key >> 32));
    out[b * 30 + t * 3 + 0] = (float)d;     // position_found [B,10,3]
    out[b * 30 + t * 3 + 1] = (float)x;
    out[b * 30 + t * 3 + 2] = (float)y;
    out[240 + b * 20 + t * 2 + 0] = v / um;        // ov0: max incl. prior (normalized u)
    out[240 + b * 20 + t * 2 + 1] = bvv / prior[d];// ov1: raw conv value
    pxy[2 * b] = x; pxy[2 * b + 1] = y;
  }
}

extern "C" void kernel_launch(void* const* d_in, const int* in_sizes, int n_in,
                              void* d_out, int out_size, void* d_ws, size_t ws_size,
                              hipStream_t stream)
{
  const float* input = (const float*)d_in[0];
  const float* filt  = (const float*)d_in[1];
  // d_in[2] (dictionary) is unused by the reference
  const float* prior = (const float*)d_in[3];
  float* out = (float*)d_out;

  char* ws = (char*)d_ws;
  u64*   packed = (u64*)(ws);                  // 8*65536*8 = 4,194,304 B
  float* u      = (float*)(ws + 4194304);      // 2,097,152 B
  float* smax   = (float*)(ws + 6291456);      // 1024 B
  int*   sidx   = (int*)  (ws + 6292480);      // 1024 B
  float* umax   = (float*)(ws + 6293504);      // 1024 B
  int*   pxy    = (int*)  (ws + 6294528);      // 64 B

  init_kernel<<<2048, 256, 0, stream>>>(packed, u, pxy);
  conv_best_kernel<<<dim3(16, NB, 4), 256, 0, stream>>>(input, filt, prior, packed);
  for (int t = 0; t < 10; ++t){
    scan_kernel<<<dim3(32, NB), 256, 0, stream>>>(packed, u, pxy, smax, sidx, umax);
    final_kernel<<<NB, 64, 0, stream>>>(packed, prior, smax, sidx, umax, pxy, out, t);
  }
}

// Round 3
// 2208.154 us; speedup vs baseline: 3.4952x; 3.4952x over previous
//
#include <hip/hip_runtime.h>

typedef unsigned long long u64;
typedef unsigned int u32;

#define NB 8
#define NPIX 65536   // 256*256

// monotone float->uint encoding (order-preserving for all reals)
__device__ __forceinline__ u32 fsort(float f){
  u32 u = __float_as_uint(f);
  return (u & 0x80000000u) ? ~u : (u | 0x80000000u);
}
__device__ __forceinline__ float funsort(u32 s){
  u32 u = (s & 0x80000000u) ? (s ^ 0x80000000u) : ~s;
  return __uint_as_float(u);
}

// ---------------- init: zero packed best-map, init use map + pos sentinels ----
__global__ void init_kernel(u64* __restrict__ packed, float* __restrict__ u,
                            int* __restrict__ pxy){
  int idx = blockIdx.x * 256 + threadIdx.x;
  if (idx < NB * NPIX){
    packed[idx] = 0ull;
    int p = idx & (NPIX - 1);
    int x = p >> 8, y = p & 255;
    u[idx] = (x >= 16 && x < 240 && y >= 16 && y < 240) ? 1.0f : 0.0f;
  }
  if (idx < 2 * NB) pxy[idx] = -100000;  // sentinel: first iter tmap==1 everywhere
}

// ---------------- conv + per-pixel max over d (fused) -----------------------
// conv[b,d,x,y] = sum_{fy,fx} input[b,(x+fy-16)%256,(y+fx-16)%256] * filt[d,fy,fx]
// 64x64 output tile per block, 16 d's; rolling 4-row register window over fy;
// filter rows via wave-uniform (scalar) global loads -> SGPR operand of v_fma.
// NOTE: no min-waves arg in launch_bounds! (256,2) caps VGPR at 128 and the
// w[4][36] window (144 regs) spills to scratch -> 23 GB of HBM traffic (R2).
__global__ __launch_bounds__(256) void conv_best_kernel(
    const float* __restrict__ input, const float* __restrict__ filt,
    const float* __restrict__ prior, u64* __restrict__ packed)
{
  __shared__ float sin_[96 * 96];
  const int tile = blockIdx.x;        // 0..15
  const int b    = blockIdx.y;        // 0..7
  const int g    = blockIdx.z;        // 0..3 (16 d's each)
  const int tX = (tile >> 2) << 6;
  const int tY = (tile & 3) << 6;
  const int tid = threadIdx.x;

  const float* inb = input + b * NPIX;
  for (int k = tid; k < 96 * 96; k += 256){
    int iy = k / 96, ix = k - iy * 96;
    int gx = (tX + iy - 16) & 255;
    int gy = (tY + ix - 16) & 255;
    sin_[k] = inb[(gx << 8) + gy];
  }
  __syncthreads();

  const int ty = tid >> 4, tx = tid & 15;
  const int oy = ty << 2, ox = tx << 2;

  float bv[16];
  int   bd[16];
  #pragma unroll
  for (int i = 0; i < 16; ++i){ bv[i] = -3e38f; bd[i] = 0; }

  float w[4][36];   // rolling input rows; ALL indices compile-time constants

  #pragma unroll 1
  for (int dl = 0; dl < 16; ++dl){
    const int d = (g << 4) + dl;
    const float* __restrict__ frow = filt + d * 1089;

    // prologue: rows oy..oy+3 -> slots 0..3
    #pragma unroll
    for (int j = 0; j < 4; ++j){
      const float4* src = (const float4*)(sin_ + (oy + j) * 96 + ox);
      #pragma unroll
      for (int q = 0; q < 9; ++q){
        float4 t = src[q];
        w[j][4*q+0] = t.x; w[j][4*q+1] = t.y; w[j][4*q+2] = t.z; w[j][4*q+3] = t.w;
      }
    }

    float acc[4][4] = {};

    // phase: window rows are slots ((P)+r)&3; after use, slot (P)&3 gets row oy+fy+4
#define CPHASE(P, DOLOAD)                                                    \
    {                                                                        \
      const int fy = fy4 + (P);                                              \
      const float* fr = frow + fy * 33;   /* wave-uniform -> s_load */       \
      _Pragma("unroll")                                                      \
      for (int fx = 0; fx < 33; ++fx){                                       \
        const float fv = fr[fx];                                             \
        _Pragma("unroll")                                                    \
        for (int r = 0; r < 4; ++r){                                         \
          _Pragma("unroll")                                                  \
          for (int c = 0; c < 4; ++c)                                        \
            acc[r][c] = fmaf(fv, w[((P) + r) & 3][fx + c], acc[r][c]);       \
        }                                                                    \
      }                                                                      \
      if (DOLOAD){                                                           \
        const float4* src = (const float4*)(sin_ + (oy + fy + 4) * 96 + ox); \
        _Pragma("unroll")                                                    \
        for (int q = 0; q < 9; ++q){                                         \
          float4 t = src[q];                                                 \
          w[(P)&3][4*q+0] = t.x; w[(P)&3][4*q+1] = t.y;                      \
          w[(P)&3][4*q+2] = t.z; w[(P)&3][4*q+3] = t.w;                      \
        }                                                                    \
      }                                                                      \
    }

    #pragma unroll 1
    for (int fy4 = 0; fy4 < 32; fy4 += 4){
      CPHASE(0, true)
      CPHASE(1, true)
      CPHASE(2, true)
      CPHASE(3, true)
    }
    { const int fy4 = 32; CPHASE(0, false) }
#undef CPHASE

    const float pr = prior[d];
    #pragma unroll
    for (int r = 0; r < 4; ++r)
      #pragma unroll
      for (int c = 0; c < 4; ++c){
        float v = acc[r][c] * pr;
        int i = (r << 2) + c;
        if (v > bv[i]){ bv[i] = v; bd[i] = d; }   // ascending d: strict > keeps smallest d
      }
  }

  u64* pb = packed + b * NPIX;
  #pragma unroll
  for (int r = 0; r < 4; ++r)
    #pragma unroll
    for (int c = 0; c < 4; ++c){
      int x = tX + oy + r, y = tY + ox + c;
      int i = (r << 2) + c;
      u64 key = ((u64)fsort(bv[i]) << 32) | (u64)(63 - bd[i]); // tie -> smaller d
      atomicMax(&pb[(x << 8) + y], key);
    }
}

// ---------------- per-iteration: apply deadzone, scan for argmax + umax -----
__global__ __launch_bounds__(256) void scan_kernel(
    const u64* __restrict__ packed, float* __restrict__ u, const int* __restrict__ pxy,
    float* __restrict__ smax, int* __restrict__ sidx, float* __restrict__ umax)
{
  const int b   = blockIdx.y;
  const int blk = blockIdx.x;          // 0..31
  const int tid = threadIdx.x;
  const int px = pxy[2 * b], py = pxy[2 * b + 1];
  const int base = blk * 2048;

  float lmax = -3e38f; int lidx = 0; float lu = 0.f;
  for (int k = tid; k < 2048; k += 256){
    const int p = base + k;
    const int idx = b * NPIX + p;
    float uu = u[idx];
    int x = p >> 8, y = p & 255;
    float dx = (float)(x - px), dy = (float)(y - py);
    float d2 = dx * dx + dy * dy;
    float t = 1.f - __expf(d2 * -0.03125f);     // 1/(2*sigma^2), sigma=4
    if (d2 <= 16.f) t = 0.f;                    // hard cutout r=4
    uu *= t;
    u[idx] = uu;
    float bvv = funsort((u32)(packed[idx] >> 32));
    float s = bvv * uu;
    if (s > lmax || (s == lmax && p < lidx)){ lmax = s; lidx = p; }
    if (uu > lu) lu = uu;
  }
  __shared__ float rmax[256]; __shared__ int rid[256]; __shared__ float rum[256];
  rmax[tid] = lmax; rid[tid] = lidx; rum[tid] = lu;
  __syncthreads();
  for (int s = 128; s > 0; s >>= 1){
    if (tid < s){
      float v2 = rmax[tid + s]; int i2 = rid[tid + s];
      if (v2 > rmax[tid] || (v2 == rmax[tid] && i2 < rid[tid])){ rmax[tid] = v2; rid[tid] = i2; }
      if (rum[tid + s] > rum[tid]) rum[tid] = rum[tid + s];
    }
    __syncthreads();
  }
  if (tid == 0){
    smax[b * 32 + blk] = rmax[0];
    sidx[b * 32 + blk] = rid[0];
    umax[b * 32 + blk] = rum[0];
  }
}

// ---------------- finalize iteration: reduce 32 partials, emit outputs ------
__global__ void final_kernel(const u64* __restrict__ packed, const float* __restrict__ prior,
    const float* __restrict__ smax, const int* __restrict__ sidx, const float* __restrict__ umax,
    int* __restrict__ pxy, float* __restrict__ out, int t)
{
  const int b = blockIdx.x;
  const int lane = threadIdx.x;   // 64 threads, entries in lanes 0..31
  float v = -3e38f; int id = 0x7fffffff; float um = 0.f;
  if (lane < 32){ v = smax[b * 32 + lane]; id = sidx[b * 32 + lane]; um = umax[b * 32 + lane]; }
  #pragma unroll
  for (int off = 32; off > 0; off >>= 1){
    float v2 = __shfl_down(v, off);
    int   i2 = __shfl_down(id, off);
    float u2 = __shfl_down(um, off);
    if (v2 > v || (v2 == v && i2 < id)){ v = v2; id = i2; }
    if (u2 > um) um = u2;
  }
  if (lane == 0){
    int x = id >> 8, y = id & 255;
    u64 key = packed[b * NPIX + id];
    int d = 63 - (int)(key & 63ull);
    float bvv = funsort((u32)(key >> 32));
    out[b * 30 + t * 3 + 0] = (float)d;     // position_found [B,10,3]
    out[b * 30 + t * 3 + 1] = (float)x;
    out[b * 30 + t * 3 + 2] = (float)y;
    out[240 + b * 20 + t * 2 + 0] = v / um;        // ov0: max incl. prior (normalized u)
    out[240 + b * 20 + t * 2 + 1] = bvv / prior[d];// ov1: raw conv value
    pxy[2 * b] = x; pxy[2 * b + 1] = y;
  }
}

extern "C" void kernel_launch(void* const* d_in, const int* in_sizes, int n_in,
                              void* d_out, int out_size, void* d_ws, size_t ws_size,
                              hipStream_t stream)
{
  const float* input = (const float*)d_in[0];
  const float* filt  = (const float*)d_in[1];
  // d_in[2] (dictionary) is unused by the reference
  const float* prior = (const float*)d_in[3];
  float* out = (float*)d_out;

  char* ws = (char*)d_ws;
  u64*   packed = (u64*)(ws);                  // 8*65536*8 = 4,194,304 B
  float* u      = (float*)(ws + 4194304);      // 2,097,152 B
  float* smax   = (float*)(ws + 6291456);      // 1024 B
  int*   sidx   = (int*)  (ws + 6292480);      // 1024 B
  float* umax   = (float*)(ws + 6293504);      // 1024 B
  int*   pxy    = (int*)  (ws + 6294528);      // 64 B

  init_kernel<<<2048, 256, 0, stream>>>(packed, u, pxy);
  conv_best_kernel<<<dim3(16, NB, 4), 256, 0, stream>>>(input, filt, prior, packed);
  for (int t = 0; t < 10; ++t){
    scan_kernel<<<dim3(32, NB), 256, 0, stream>>>(packed, u, pxy, smax, sidx, umax);
    final_kernel<<<NB, 64, 0, stream>>>(packed, prior, smax, sidx, umax, pxy, out, t);
  }
}

// Round 4
// 796.684 us; speedup vs baseline: 9.6875x; 2.7717x over previous
//
#include <hip/hip_runtime.h>

typedef unsigned long long u64;
typedef unsigned int u32;

#define NB 8
#define NPIX 65536   // 256*256

// monotone float->uint encoding (order-preserving for all reals)
__device__ __forceinline__ u32 fsort(float f){
  u32 u = __float_as_uint(f);
  return (u & 0x80000000u) ? ~u : (u | 0x80000000u);
}
__device__ __forceinline__ float funsort(u32 s){
  u32 u = (s & 0x80000000u) ? (s ^ 0x80000000u) : ~s;
  return __uint_as_float(u);
}

// ---------------- init: zero packed best-map, init use map + pos sentinels ----
__global__ void init_kernel(u64* __restrict__ packed, float* __restrict__ u,
                            int* __restrict__ pxy){
  int idx = blockIdx.x * 256 + threadIdx.x;
  if (idx < NB * NPIX){
    packed[idx] = 0ull;
    int p = idx & (NPIX - 1);
    int x = p >> 8, y = p & 255;
    u[idx] = (x >= 16 && x < 240 && y >= 16 && y < 240) ? 1.0f : 0.0f;
  }
  if (idx < 2 * NB) pxy[idx] = -100000;  // sentinel: first iter tmap==1 everywhere
}

// ---------------- conv + per-pixel max over d (fused) -----------------------
// conv[b,d,x,y] = sum_{fy,fx} input[b,(x+fy-16)%256,(y+fx-16)%256] * filt[d,fy,fx]
// Block: 16-row x 256-col output stripe for one b, 16 d's.
// Thread: 1 row x 16 cols. Per fy it loads a 48-float window (12 x b128) from
// a full-width 48x256 LDS halo, XOR-swizzled at float4-block granularity:
//   swz(B,row) = B ^ ((B>>3)&7) ^ (row&7)
// -> 16 tx-lanes spread 2 per bank-slot (conflict-free floor), wrap mod 256 free.
// Registers: w[48]+acc[16]+bv/bd[32]+pre[12] ~ 150 VGPR, no spill (R3 lesson:
// w[4][36] rolling window demanded ~300 regs -> 1.3 GB scratch traffic).
__global__ __launch_bounds__(256) void conv_best_kernel(
    const float* __restrict__ input, const float* __restrict__ filt,
    const float* __restrict__ prior, u64* __restrict__ packed)
{
  __shared__ float sin_[48 * 256];
  const int tile = blockIdx.x;        // 0..15 (output rows tile*16..tile*16+15)
  const int b    = blockIdx.y;        // 0..7
  const int g    = blockIdx.z;        // 0..3 (16 d's each)
  const int tX = tile << 4;
  const int tid = threadIdx.x;

  const float* inb = input + b * NPIX;
  // stage 48 full rows (input rows tX-16 .. tX+31 mod 256), swizzled
  for (int k = tid; k < 48 * 64; k += 256){
    int row = k >> 6;                  // 0..47
    int B   = k & 63;                  // 16B block within row
    int gx  = (tX - 16 + row) & 255;
    float4 v = *(const float4*)(inb + (gx << 8) + (B << 2));
    int Bs = B ^ ((B >> 3) & 7) ^ (row & 7);
    *(float4*)(sin_ + row * 256 + (Bs << 2)) = v;
  }
  __syncthreads();

  const int ty = tid >> 4;            // 0..15 output row within stripe
  const int tx = tid & 15;            // 0..15 -> cols tx*16..tx*16+15

  // precompute swizzle-prefix for the 12 window blocks (fy-independent)
  int pre[12];
  #pragma unroll
  for (int q = 0; q < 12; ++q){
    int Bq = ((tx << 2) + q + 60) & 63;   // block of col tx*16-16+4q (mod 256)
    pre[q] = Bq ^ ((Bq >> 3) & 7);
  }

  float bv[16];
  int   bd[16];
  #pragma unroll
  for (int i = 0; i < 16; ++i){ bv[i] = -3e38f; bd[i] = 0; }

  #pragma unroll 1
  for (int dl = 0; dl < 16; ++dl){
    const int d = (g << 4) + dl;
    const float* __restrict__ frow = filt + d * 1089;

    float acc[16] = {};

    #pragma unroll 1
    for (int fy = 0; fy < 33; ++fy){
      const int row = ty + fy;             // LDS row 0..47
      const int rm  = row & 7;
      const float* base = sin_ + row * 256;

      float w[48];
      #pragma unroll
      for (int q = 0; q < 12; ++q){
        float4 v = *(const float4*)(base + ((pre[q] ^ rm) << 2));
        w[4*q+0] = v.x; w[4*q+1] = v.y; w[4*q+2] = v.z; w[4*q+3] = v.w;
      }

      const float* fr = frow + fy * 33;    // wave-uniform -> s_load
      #pragma unroll
      for (int fx = 0; fx < 33; ++fx){
        const float fv = fr[fx];
        #pragma unroll
        for (int c = 0; c < 16; ++c)
          acc[c] = fmaf(fv, w[c + fx], acc[c]);
      }
    }

    const float pr = prior[d];
    #pragma unroll
    for (int c = 0; c < 16; ++c){
      float v = acc[c] * pr;
      if (v > bv[c]){ bv[c] = v; bd[c] = d; }   // ascending d: strict > keeps smallest d
    }
  }

  u64* pb = packed + b * NPIX;
  const int x = tX + ty;
  #pragma unroll
  for (int c = 0; c < 16; ++c){
    int y = (tx << 4) + c;
    u64 key = ((u64)fsort(bv[c]) << 32) | (u64)(63 - bd[c]); // tie -> smaller d
    atomicMax(&pb[(x << 8) + y], key);
  }
}

// ---------------- per-iteration: apply deadzone, scan for argmax + umax -----
__global__ __launch_bounds__(256) void scan_kernel(
    const u64* __restrict__ packed, float* __restrict__ u, const int* __restrict__ pxy,
    float* __restrict__ smax, int* __restrict__ sidx, float* __restrict__ umax)
{
  const int b   = blockIdx.y;
  const int blk = blockIdx.x;          // 0..31
  const int tid = threadIdx.x;
  const int px = pxy[2 * b], py = pxy[2 * b + 1];
  const int base = blk * 2048;

  float lmax = -3e38f; int lidx = 0; float lu = 0.f;
  for (int k = tid; k < 2048; k += 256){
    const int p = base + k;
    const int idx = b * NPIX + p;
    float uu = u[idx];
    int x = p >> 8, y = p & 255;
    float dx = (float)(x - px), dy = (float)(y - py);
    float d2 = dx * dx + dy * dy;
    float t = 1.f - __expf(d2 * -0.03125f);     // 1/(2*sigma^2), sigma=4
    if (d2 <= 16.f) t = 0.f;                    // hard cutout r=4
    uu *= t;
    u[idx] = uu;
    float bvv = funsort((u32)(packed[idx] >> 32));
    float s = bvv * uu;
    if (s > lmax || (s == lmax && p < lidx)){ lmax = s; lidx = p; }
    if (uu > lu) lu = uu;
  }
  __shared__ float rmax[256]; __shared__ int rid[256]; __shared__ float rum[256];
  rmax[tid] = lmax; rid[tid] = lidx; rum[tid] = lu;
  __syncthreads();
  for (int s = 128; s > 0; s >>= 1){
    if (tid < s){
      float v2 = rmax[tid + s]; int i2 = rid[tid + s];
      if (v2 > rmax[tid] || (v2 == rmax[tid] && i2 < rid[tid])){ rmax[tid] = v2; rid[tid] = i2; }
      if (rum[tid + s] > rum[tid]) rum[tid] = rum[tid + s];
    }
    __syncthreads();
  }
  if (tid == 0){
    smax[b * 32 + blk] = rmax[0];
    sidx[b * 32 + blk] = rid[0];
    umax[b * 32 + blk] = rum[0];
  }
}

// ---------------- finalize iteration: reduce 32 partials, emit outputs ------
__global__ void final_kernel(const u64* __restrict__ packed, const float* __restrict__ prior,
    const float* __restrict__ smax, const int* __restrict__ sidx, const float* __restrict__ umax,
    int* __restrict__ pxy, float* __restrict__ out, int t)
{
  const int b = blockIdx.x;
  const int lane = threadIdx.x;   // 64 threads, entries in lanes 0..31
  float v = -3e38f; int id = 0x7fffffff; float um = 0.f;
  if (lane < 32){ v = smax[b * 32 + lane]; id = sidx[b * 32 + lane]; um = umax[b * 32 + lane]; }
  #pragma unroll
  for (int off = 32; off > 0; off >>= 1){
    float v2 = __shfl_down(v, off);
    int   i2 = __shfl_down(id, off);
    float u2 = __shfl_down(um, off);
    if (v2 > v || (v2 == v && i2 < id)){ v = v2; id = i2; }
    if (u2 > um) um = u2;
  }
  if (lane == 0){
    int x = id >> 8, y = id & 255;
    u64 key = packed[b * NPIX + id];
    int d = 63 - (int)(key & 63ull);
    float bvv = funsort((u32)(key >> 32));
    out[b * 30 + t * 3 + 0] = (float)d;     // position_found [B,10,3]
    out[b * 30 + t * 3 + 1] = (float)x;
    out[b * 30 + t * 3 + 2] = (float)y;
    out[240 + b * 20 + t * 2 + 0] = v / um;        // ov0: max incl. prior (normalized u)
    out[240 + b * 20 + t * 2 + 1] = bvv / prior[d];// ov1: raw conv value
    pxy[2 * b] = x; pxy[2 * b + 1] = y;
  }
}

extern "C" void kernel_launch(void* const* d_in, const int* in_sizes, int n_in,
                              void* d_out, int out_size, void* d_ws, size_t ws_size,
                              hipStream_t stream)
{
  const float* input = (const float*)d_in[0];
  const float* filt  = (const float*)d_in[1];
  // d_in[2] (dictionary) is unused by the reference
  const float* prior = (const float*)d_in[3];
  float* out = (float*)d_out;

  char* ws = (char*)d_ws;
  u64*   packed = (u64*)(ws);                  // 8*65536*8 = 4,194,304 B
  float* u      = (float*)(ws + 4194304);      // 2,097,152 B
  float* smax   = (float*)(ws + 6291456);      // 1024 B
  int*   sidx   = (int*)  (ws + 6292480);      // 1024 B
  float* umax   = (float*)(ws + 6293504);      // 1024 B
  int*   pxy    = (int*)  (ws + 6294528);      // 64 B

  init_kernel<<<2048, 256, 0, stream>>>(packed, u, pxy);
  conv_best_kernel<<<dim3(16, NB, 4), 256, 0, stream>>>(input, filt, prior, packed);
  for (int t = 0; t < 10; ++t){
    scan_kernel<<<dim3(32, NB), 256, 0, stream>>>(packed, u, pxy, smax, sidx, umax);
    final_kernel<<<NB, 64, 0, stream>>>(packed, prior, smax, sidx, umax, pxy, out, t);
  }
}